// Round 4
// baseline (598.811 us; speedup 1.0000x reference)
//
#include <hip/hip_runtime.h>
#include <hip/hip_bf16.h>
#include <stdint.h>

#define TOKENS 2048
#define HDIM 1024
#define FDIM 3584
#define NEXP 8
#define BK 32

typedef __attribute__((ext_vector_type(8))) short short8;
typedef __attribute__((ext_vector_type(4))) float floatx4;

#define AS1 __attribute__((address_space(1)))
#define AS3 __attribute__((address_space(3)))

__device__ __forceinline__ void glds16(const void* g, void* l) {
  __builtin_amdgcn_global_load_lds((const AS1 void*)g, (AS3 void*)l, 16, 0, 0);
}

__device__ __forceinline__ unsigned short f2bf(float f) {
  union { float f; unsigned int u; } c; c.f = f;
  unsigned int u = c.u;
  u += 0x7fffu + ((u >> 16) & 1u);
  return (unsigned short)(u >> 16);
}

__device__ __forceinline__ unsigned int pk2bf(float a, float b) {
  __hip_bfloat162 h = __float22bfloat162_rn(make_float2(a, b));
  union { __hip_bfloat162 h; unsigned int u; } c; c.h = h;
  return c.u;
}

// ---------------- gating ----------------
__global__ void gate_kernel(const float* __restrict__ x,
                            const float* __restrict__ gw,
                            int* __restrict__ top_e,
                            float* __restrict__ top_w,
                            int* __restrict__ count) {
  int wv = threadIdx.x >> 6;
  int lane = threadIdx.x & 63;
  int t = blockIdx.x * 4 + wv;
  if (t >= TOKENS) return;
  float p[NEXP];
#pragma unroll
  for (int e = 0; e < NEXP; e++) p[e] = 0.f;
  const float* xr = x + (size_t)t * HDIM;
  for (int h = lane; h < HDIM; h += 64) {
    float xv = xr[h];
    const float4* g4 = (const float4*)(gw + (size_t)h * NEXP);
    float4 a = g4[0], b = g4[1];
    p[0] += xv * a.x; p[1] += xv * a.y; p[2] += xv * a.z; p[3] += xv * a.w;
    p[4] += xv * b.x; p[5] += xv * b.y; p[6] += xv * b.z; p[7] += xv * b.w;
  }
#pragma unroll
  for (int e = 0; e < NEXP; e++) {
#pragma unroll
    for (int off = 32; off > 0; off >>= 1) p[e] += __shfl_xor(p[e], off, 64);
  }
  if (lane == 0) {
    int i0 = 0;
    for (int e = 1; e < NEXP; e++) if (p[e] > p[i0]) i0 = e;
    int i1 = (i0 == 0) ? 1 : 0;
    for (int e = 0; e < NEXP; e++) if (e != i0 && p[e] > p[i1]) i1 = e;
    float l0 = p[i0], l1 = p[i1];
    float e1 = __expf(l1 - l0);
    float s = 1.f + e1;
    top_e[t * 2] = i0; top_e[t * 2 + 1] = i1;
    top_w[t * 2] = 1.f / s; top_w[t * 2 + 1] = e1 / s;
    atomicAdd(&count[i0], 1);
    atomicAdd(&count[i1], 1);
  }
}

__global__ void offsets_kernel(const int* __restrict__ count,
                               int* __restrict__ offs,
                               int* __restrict__ cursor) {
  if (threadIdx.x == 0 && blockIdx.x == 0) {
    int o = 0;
    for (int e = 0; e < NEXP; e++) { offs[e] = o; cursor[e] = o; o += count[e]; }
  }
}

__global__ void scatter_kernel(const int* __restrict__ top_e,
                               int* __restrict__ cursor,
                               int* __restrict__ tok_of,
                               int* __restrict__ slot_of) {
  int t = blockIdx.x * blockDim.x + threadIdx.x;
  if (t >= TOKENS) return;
#pragma unroll
  for (int k = 0; k < 2; k++) {
    int e = top_e[t * 2 + k];
    int g = atomicAdd(&cursor[e], 1);
    tok_of[g] = t;
    slot_of[t * 2 + k] = g;
  }
}

__global__ void xconv_kernel(const float* __restrict__ x,
                             unsigned short* __restrict__ xbf) {
  int i = (blockIdx.x * blockDim.x + threadIdx.x) * 4;
  float4 v = *(const float4*)(x + i);
  uint2 pk;
  pk.x = pk2bf(v.x, v.y);
  pk.y = pk2bf(v.z, v.w);
  *(uint2*)(xbf + i) = pk;
}

// ---------------- weight fp32 -> bf16 (88M elements, 3 tensors) ----------------
#define WELEMS 29360128          // 8*3584*1024
#define WBLK (WELEMS / 2048)     // 14336 blocks per tensor, 8 floats/thread

__global__ void wconv_kernel(const float* __restrict__ w1,
                             const float* __restrict__ w3,
                             const float* __restrict__ w2,
                             unsigned short* __restrict__ w1b,
                             unsigned short* __restrict__ w3b,
                             unsigned short* __restrict__ w2b) {
  int b = blockIdx.x;
  const float* src; unsigned short* dst;
  if (b < WBLK) { src = w1; dst = w1b; }
  else if (b < 2 * WBLK) { src = w3; dst = w3b; b -= WBLK; }
  else { src = w2; dst = w2b; b -= 2 * WBLK; }
  size_t i = ((size_t)b * 256 + threadIdx.x) * 8;
  float4 v0 = *(const float4*)(src + i);
  float4 v1 = *(const float4*)(src + i + 4);
  uint4 o;
  o.x = pk2bf(v0.x, v0.y); o.y = pk2bf(v0.z, v0.w);
  o.z = pk2bf(v1.x, v1.y); o.w = pk2bf(v1.z, v1.w);
  *(uint4*)(dst + i) = o;
}

// ---------------- GEMM1: act = silu(X w1^T) * (X w3^T), 128x64, bf16, dbuf ----------------
#define G1_BM 128
#define G1_BF 64

__global__ __launch_bounds__(256, 4)
void gemm1_kernel(const unsigned short* __restrict__ xbf,
                  const unsigned short* __restrict__ w1b,
                  const unsigned short* __restrict__ w3b,
                  const int* __restrict__ count,
                  const int* __restrict__ offs,
                  const int* __restrict__ tok_of,
                  unsigned short* __restrict__ act) {
  int e = blockIdx.z;
  int cnt = count[e];
  int m0 = blockIdx.y * G1_BM;
  if (m0 >= cnt) return;
  int f0 = blockIdx.x * G1_BF;
  int off_e = offs[e];

  __shared__ __align__(16) unsigned short sA[2][G1_BM * 32];   // 2 x 8 KB
  __shared__ __align__(16) unsigned short sB1[2][G1_BF * 32];  // 2 x 4 KB
  __shared__ __align__(16) unsigned short sB3[2][G1_BF * 32];  // 2 x 4 KB

  int tid = threadIdx.x;
  int lane = tid & 63, wv = tid >> 6;

  // A staging: 512 chunks of 16B, 2 per thread, chunk-swizzled
  const unsigned short* ag[2];
#pragma unroll
  for (int p = 0; p < 2; p++) {
    int c = tid + p * 256;
    int row = c >> 2, slot = c & 3;
    int gch = slot ^ ((row >> 1) & 3);
    int r = m0 + row;
    int tok = tok_of[off_e + (r < cnt ? r : 0)];
    ag[p] = xbf + (size_t)tok * HDIM + gch * 8;
  }
  unsigned aoff = (unsigned)(wv * 64) * 16;

  // B staging: 256 chunks each, 1 per thread
  int brow = tid >> 2, bslot = tid & 3;
  int bgch = bslot ^ ((brow >> 1) & 3);
  const unsigned short* b1g = w1b + ((size_t)e * FDIM + f0 + brow) * HDIM + bgch * 8;
  const unsigned short* b3g = w3b + ((size_t)e * FDIM + f0 + brow) * HDIM + bgch * 8;
  unsigned boff = (unsigned)(wv * 64) * 16;

  int lrow = lane & 15, quad = lane >> 4;
  int wm = wv >> 1, wn = wv & 1;

  floatx4 acc1[4][2], acc3[4][2];
#pragma unroll
  for (int i = 0; i < 4; i++)
#pragma unroll
    for (int j = 0; j < 2; j++) {
      acc1[i][j] = (floatx4){0.f, 0.f, 0.f, 0.f};
      acc3[i][j] = (floatx4){0.f, 0.f, 0.f, 0.f};
    }

  // prologue: tile 0 -> buf 0
#pragma unroll
  for (int p = 0; p < 2; p++)
    glds16(ag[p], (char*)sA[0] + aoff + p * 4096);
  glds16(b1g, (char*)sB1[0] + boff);
  glds16(b3g, (char*)sB3[0] + boff);
  __syncthreads();

  int cur = 0;
  for (int k0 = 0; k0 < HDIM; k0 += BK) {
    int kn = k0 + BK;
    if (kn < HDIM) {   // prefetch next tile into the other buffer
      int nxt = cur ^ 1;
#pragma unroll
      for (int p = 0; p < 2; p++)
        glds16(ag[p] + kn, (char*)sA[nxt] + aoff + p * 4096);
      glds16(b1g + kn, (char*)sB1[nxt] + boff);
      glds16(b3g + kn, (char*)sB3[nxt] + boff);
    }

    short8 af[4], b1f[2], b3f[2];
#pragma unroll
    for (int ms = 0; ms < 4; ms++) {
      int r = wm * 64 + ms * 16 + lrow;
      int sl = quad ^ ((r >> 1) & 3);
      af[ms] = *(const short8*)(sA[cur] + r * 32 + sl * 8);
    }
#pragma unroll
    for (int ns = 0; ns < 2; ns++) {
      int r = wn * 32 + ns * 16 + lrow;
      int sl = quad ^ ((r >> 1) & 3);
      b1f[ns] = *(const short8*)(sB1[cur] + r * 32 + sl * 8);
      b3f[ns] = *(const short8*)(sB3[cur] + r * 32 + sl * 8);
    }
#pragma unroll
    for (int ms = 0; ms < 4; ms++)
#pragma unroll
      for (int ns = 0; ns < 2; ns++) {
        acc1[ms][ns] = __builtin_amdgcn_mfma_f32_16x16x32_bf16(af[ms], b1f[ns], acc1[ms][ns], 0, 0, 0);
        acc3[ms][ns] = __builtin_amdgcn_mfma_f32_16x16x32_bf16(af[ms], b3f[ns], acc3[ms][ns], 0, 0, 0);
      }
    __syncthreads();   // drains prefetch vmcnt + protects buffer swap
    cur ^= 1;
  }

#pragma unroll
  for (int ms = 0; ms < 4; ms++) {
#pragma unroll
    for (int reg = 0; reg < 4; reg++) {
      int slot = m0 + wm * 64 + ms * 16 + quad * 4 + reg;
      if (slot < cnt) {
        unsigned short* ar = act + (size_t)(off_e + slot) * FDIM + f0 + wn * 32;
#pragma unroll
        for (int ns = 0; ns < 2; ns++) {
          float h = acc1[ms][ns][reg];
          float g = acc3[ms][ns][reg];
          float a = h / (1.f + __expf(-h)) * g;
          ar[ns * 16 + lrow] = f2bf(a);
        }
      }
    }
  }
}

// ---------------- GEMM2: part[sk] = act w2^T (K-slice), 128x128, bf16, dbuf ----------------
#define G2_BM 128
#define G2_BN 128
#define SPLITK 4
#define G2_KS (FDIM / SPLITK)   // 896

__global__ __launch_bounds__(256, 4)
void gemm2_kernel(const unsigned short* __restrict__ act,
                  const unsigned short* __restrict__ w2b,
                  const int* __restrict__ count,
                  const int* __restrict__ offs,
                  float* __restrict__ part) {
  int zz = blockIdx.z;
  int e = zz & 7, sk = zz >> 3;
  int cnt = count[e];
  int m0 = blockIdx.y * G2_BM;
  if (m0 >= cnt) return;
  int h0 = blockIdx.x * G2_BN;
  int off_e = offs[e];
  int kb = sk * G2_KS;

  __shared__ __align__(16) unsigned short sA[2][G2_BM * 32];  // 2 x 8 KB
  __shared__ __align__(16) unsigned short sB[2][G2_BN * 32];  // 2 x 8 KB

  int tid = threadIdx.x;
  int lane = tid & 63, wv = tid >> 6;

  const unsigned short* ag[2];
  const unsigned short* bg[2];
#pragma unroll
  for (int p = 0; p < 2; p++) {
    int c = tid + p * 256;
    int row = c >> 2, slot = c & 3;
    int gch = slot ^ ((row >> 1) & 3);
    {
      int r = m0 + row;
      int rr = (r < cnt ? r : 0);
      ag[p] = act + (size_t)(off_e + rr) * FDIM + kb + gch * 8;
    }
    bg[p] = w2b + ((size_t)e * HDIM + h0 + row) * FDIM + kb + gch * 8;
  }
  unsigned off16 = (unsigned)(wv * 64) * 16;

  int lrow = lane & 15, quad = lane >> 4;
  int wm = wv >> 1, wn = wv & 1;

  floatx4 acc[4][4];
#pragma unroll
  for (int i = 0; i < 4; i++)
#pragma unroll
    for (int j = 0; j < 4; j++) acc[i][j] = (floatx4){0.f, 0.f, 0.f, 0.f};

  // prologue
#pragma unroll
  for (int p = 0; p < 2; p++) {
    glds16(ag[p], (char*)sA[0] + off16 + p * 4096);
    glds16(bg[p], (char*)sB[0] + off16 + p * 4096);
  }
  __syncthreads();

  int cur = 0;
  for (int k0 = 0; k0 < G2_KS; k0 += BK) {
    int kn = k0 + BK;
    if (kn < G2_KS) {
      int nxt = cur ^ 1;
#pragma unroll
      for (int p = 0; p < 2; p++) {
        glds16(ag[p] + kn, (char*)sA[nxt] + off16 + p * 4096);
        glds16(bg[p] + kn, (char*)sB[nxt] + off16 + p * 4096);
      }
    }

    short8 af[4], bf[4];
#pragma unroll
    for (int ms = 0; ms < 4; ms++) {
      int r = wm * 64 + ms * 16 + lrow;
      int sl = quad ^ ((r >> 1) & 3);
      af[ms] = *(const short8*)(sA[cur] + r * 32 + sl * 8);
    }
#pragma unroll
    for (int ns = 0; ns < 4; ns++) {
      int r = wn * 64 + ns * 16 + lrow;
      int sl = quad ^ ((r >> 1) & 3);
      bf[ns] = *(const short8*)(sB[cur] + r * 32 + sl * 8);
    }
#pragma unroll
    for (int ms = 0; ms < 4; ms++)
#pragma unroll
      for (int ns = 0; ns < 4; ns++)
        acc[ms][ns] = __builtin_amdgcn_mfma_f32_16x16x32_bf16(af[ms], bf[ns], acc[ms][ns], 0, 0, 0);
    __syncthreads();
    cur ^= 1;
  }

#pragma unroll
  for (int ms = 0; ms < 4; ms++) {
#pragma unroll
    for (int reg = 0; reg < 4; reg++) {
      int slot = m0 + wm * 64 + ms * 16 + quad * 4 + reg;
      if (slot < cnt) {
        float* crow = part + ((size_t)sk * 4096 + off_e + slot) * HDIM + h0 + wn * 64;
#pragma unroll
        for (int ns = 0; ns < 4; ns++)
          crow[ns * 16 + lrow] = acc[ms][ns][reg];
      }
    }
  }
}

// ---------------- combine ----------------
__global__ void combine_kernel(const float* __restrict__ part,
                               const int* __restrict__ slot_of,
                               const float* __restrict__ top_w,
                               float* __restrict__ out) {
  int t = blockIdx.x;
  int g0 = slot_of[t * 2], g1 = slot_of[t * 2 + 1];
  float w0 = top_w[t * 2], w1 = top_w[t * 2 + 1];
  int i = threadIdx.x;
  float4 s0 = {0.f, 0.f, 0.f, 0.f}, s1 = {0.f, 0.f, 0.f, 0.f};
#pragma unroll
  for (int sk = 0; sk < SPLITK; sk++) {
    float4 a = ((const float4*)(part + ((size_t)sk * 4096 + g0) * HDIM))[i];
    float4 b = ((const float4*)(part + ((size_t)sk * 4096 + g1) * HDIM))[i];
    s0.x += a.x; s0.y += a.y; s0.z += a.z; s0.w += a.w;
    s1.x += b.x; s1.y += b.y; s1.z += b.z; s1.w += b.w;
  }
  float4 r;
  r.x = w0 * s0.x + w1 * s1.x;
  r.y = w0 * s0.y + w1 * s1.y;
  r.z = w0 * s0.z + w1 * s1.z;
  r.w = w0 * s0.w + w1 * s1.w;
  ((float4*)(out + (size_t)t * HDIM))[i] = r;
}

// ---------------- launcher ----------------
extern "C" void kernel_launch(void* const* d_in, const int* in_sizes, int n_in,
                              void* d_out, int out_size, void* d_ws, size_t ws_size,
                              hipStream_t stream) {
  const float* x  = (const float*)d_in[0];
  const float* gw = (const float*)d_in[1];
  const float* w1 = (const float*)d_in[2];
  const float* w3 = (const float*)d_in[3];
  const float* w2 = (const float*)d_in[4];
  float* out = (float*)d_out;

  char* ws = (char*)d_ws;
  // layout (MiB): [36,92) w1bf | [92,148) w3bf | [148,204) w2bf
  //               [204,232) act | [232,236) xbf | [36,100) part (aliases w1/w3 bf,
  //               dead after gemm1 — stream-ordered) | [236,...) small
  unsigned short* w1bf = (unsigned short*)(ws + (36ull << 20));
  unsigned short* w3bf = (unsigned short*)(ws + (92ull << 20));
  unsigned short* w2bf = (unsigned short*)(ws + (148ull << 20));
  unsigned short* act  = (unsigned short*)(ws + (204ull << 20));
  unsigned short* xbf  = (unsigned short*)(ws + (232ull << 20));
  float* part = (float*)(ws + (36ull << 20));
  char* sml = ws + (236ull << 20);
  float* top_w = (float*)sml;
  int* top_e   = (int*)(sml + 16384);
  int* slot_of = (int*)(sml + 32768);
  int* tok_of  = (int*)(sml + 49152);
  int* count   = (int*)(sml + 65536);
  int* offs    = (int*)(sml + 65536 + 32);
  int* cursor  = (int*)(sml + 65536 + 64);

  hipMemsetAsync(count, 0, 96, stream);

  gate_kernel<<<TOKENS / 4, 256, 0, stream>>>(x, gw, top_e, top_w, count);
  offsets_kernel<<<1, 64, 0, stream>>>(count, offs, cursor);
  scatter_kernel<<<TOKENS / 256, 256, 0, stream>>>(top_e, cursor, tok_of, slot_of);
  xconv_kernel<<<(TOKENS * HDIM) / (256 * 4), 256, 0, stream>>>(x, xbf);
  wconv_kernel<<<3 * WBLK, 256, 0, stream>>>(w1, w3, w2, w1bf, w3bf, w2bf);
  gemm1_kernel<<<dim3(FDIM / G1_BF, TOKENS / G1_BM, NEXP), 256, 0, stream>>>(
      xbf, w1bf, w3bf, count, offs, tok_of, act);
  gemm2_kernel<<<dim3(HDIM / G2_BN, TOKENS / G2_BM, NEXP * SPLITK), 256, 0, stream>>>(
      act, w2bf, count, offs, part);
  combine_kernel<<<TOKENS, 256, 0, stream>>>(part, slot_of, top_w, out);
}